// Round 5
// baseline (252.578 us; speedup 1.0000x reference)
//
#include <hip/hip_runtime.h>

typedef __bf16 bf16;
typedef __bf16 bf16x4 __attribute__((ext_vector_type(4)));
typedef __bf16 bf16x8 __attribute__((ext_vector_type(8)));
typedef float  f32x4  __attribute__((ext_vector_type(4)));
typedef int    int4v  __attribute__((ext_vector_type(4)));

#define NTOK 4096
#define NH   12
#define HD   64
#define CDIM 768

// C^-0.5 * log2(e), folded into Q at projection time
#define K2SCALE 0.05205928442089389f

// XOR-swizzled LDS addressing: rows are 64 bf16 = 128 B = 8 x 16B blocks.
// block' = block ^ (row & 7). Conflict-free for b128 staging writes, b128
// fragment reads, b64 P writes (residual counter floor is an artifact).
__device__ __forceinline__ bf16* swz(bf16* base, int row, int byteoff) {
  return (bf16*)((char*)base + row * 128 +
                 ((((byteoff >> 4) ^ (row & 7)) << 4) | (byteoff & 15)));
}
__device__ __forceinline__ const bf16* swz(const bf16* base, int row, int byteoff) {
  return (const bf16*)((const char*)base + row * 128 +
                 ((((byteoff >> 4) ^ (row & 7)) << 4) | (byteoff & 15)));
}

// ---------------------------------------------------------------------------
// 1) fp32 -> bf16 cast for x, Wq, Wk
// ---------------------------------------------------------------------------
__global__ __launch_bounds__(256) void cast_kernel(
    const float* __restrict__ x, const float* __restrict__ wq, const float* __restrict__ wk,
    bf16* __restrict__ xb, bf16* __restrict__ wqb, bf16* __restrict__ wkb,
    long nx, long nw) {
  long i4 = ((long)blockIdx.x * 256 + threadIdx.x) * 4;
  if (i4 >= nx + 2 * nw) return;
  const float* src; bf16* dst;
  if (i4 < nx)            { src = x  + i4;            dst = xb  + i4; }
  else if (i4 < nx + nw)  { src = wq + (i4 - nx);     dst = wqb + (i4 - nx); }
  else                    { src = wk + (i4 - nx - nw); dst = wkb + (i4 - nx - nw); }
  f32x4 v = *(const f32x4*)src;
  *(bf16x4*)dst = __builtin_convertvector(v, bf16x4);
}

// ---------------------------------------------------------------------------
// 2) projection GEMM: y[m,j] = sum_k x[m,k] * W[j,k]   (y = x @ W^T)
//    tile 128x128, BK=64, reg-prefetch staging, swizzled LDS.
//    blockIdx.z: 0->Q(scaled), 1->K. out layout [B, H, N, 64]
// ---------------------------------------------------------------------------
__global__ __launch_bounds__(256) void proj_kernel(
    const bf16* __restrict__ xb, const bf16* __restrict__ wqb, const bf16* __restrict__ wkb,
    bf16* __restrict__ Qb, bf16* __restrict__ Kb) {
  __shared__ __align__(16) bf16 Ap[128 * 64];
  __shared__ __align__(16) bf16 Bp[128 * 64];
  const int tid = threadIdx.x;
  const int w = tid >> 6, lane = tid & 63, l15 = lane & 15, quad = lane >> 4;
  const int m0 = blockIdx.x * 128;
  const int j0 = blockIdx.y * 128;
  const bf16* W   = blockIdx.z ? wkb : wqb;
  bf16*       Out = blockIdx.z ? Kb  : Qb;
  const float oscale = blockIdx.z ? 1.0f : K2SCALE;

  // per-thread staging geometry: rows (tid>>3)+i*32, 16B chunk (tid&7)
  const int srow = tid >> 3, scb = (tid & 7) * 16, soff = (tid & 7) * 8;
  const bf16* pa = xb + (long)(m0 + srow) * CDIM + soff;
  const bf16* pb = W  + (long)(j0 + srow) * CDIM + soff;

  f32x4 acc[2][8] = {};
  int4v rA[4], rB[4];
#pragma unroll
  for (int i = 0; i < 4; ++i) {
    rA[i] = *(const int4v*)(pa + (long)i * 32 * CDIM);
    rB[i] = *(const int4v*)(pb + (long)i * 32 * CDIM);
  }

  for (int kt = 0; kt < CDIM / 64; ++kt) {
    __syncthreads();  // previous tile's LDS reads done
#pragma unroll
    for (int i = 0; i < 4; ++i) {
      *(int4v*)swz(Ap, srow + i * 32, scb) = rA[i];
      *(int4v*)swz(Bp, srow + i * 32, scb) = rB[i];
    }
    __syncthreads();
    // prefetch next K-slice while computing this one
    const long koff = (long)((kt == CDIM / 64 - 1) ? kt : kt + 1) * 64;
#pragma unroll
    for (int i = 0; i < 4; ++i) {
      rA[i] = *(const int4v*)(pa + (long)i * 32 * CDIM + koff);
      rB[i] = *(const int4v*)(pb + (long)i * 32 * CDIM + koff);
    }
#pragma unroll
    for (int kk = 0; kk < 2; ++kk) {
      bf16x8 a[2], b[8];
#pragma unroll
      for (int rt = 0; rt < 2; ++rt)
        a[rt] = *(const bf16x8*)swz(Ap, w * 32 + rt * 16 + l15, kk * 64 + quad * 16);
#pragma unroll
      for (int ct = 0; ct < 8; ++ct)
        b[ct] = *(const bf16x8*)swz(Bp, ct * 16 + l15, kk * 64 + quad * 16);
#pragma unroll
      for (int rt = 0; rt < 2; ++rt)
#pragma unroll
        for (int ct = 0; ct < 8; ++ct)
          acc[rt][ct] = __builtin_amdgcn_mfma_f32_16x16x32_bf16(a[rt], b[ct], acc[rt][ct], 0, 0, 0);
    }
  }
#pragma unroll
  for (int rt = 0; rt < 2; ++rt)
#pragma unroll
    for (int ct = 0; ct < 8; ++ct)
#pragma unroll
      for (int reg = 0; reg < 4; ++reg) {
        int m = m0 + w * 32 + rt * 16 + quad * 4 + reg;
        int j = j0 + ct * 16 + l15;
        int b = m >> 12, n = m & (NTOK - 1);
        int h = j >> 6, d = j & (HD - 1);
        Out[(((long)(b * NH + h) * NTOK + n) << 6) + d] = (bf16)(acc[rt][ct][reg] * oscale);
      }
}

// ---------------------------------------------------------------------------
// 3) K [B,H,N,64] -> Kt [B,H,64,N]
// ---------------------------------------------------------------------------
__global__ __launch_bounds__(256) void transpose_kernel(
    const bf16* __restrict__ Kb, bf16* __restrict__ Ktb) {
  __shared__ __align__(16) bf16 T[64 * 72];
  const int tid = threadIdx.x;
  const int n0 = blockIdx.x * 64;
  const long bh = blockIdx.y;
#pragma unroll
  for (int i = 0; i < 2; ++i) {
    int c = tid + i * 256;
    int row = c >> 3, off = (c & 7) * 8;
    bf16x8 v = *(const bf16x8*)(Kb + ((bh << 12) + n0 + row) * HD + off);
#pragma unroll
    for (int e = 0; e < 8; ++e) T[(off + e) * 72 + row] = v[e];
  }
  __syncthreads();
#pragma unroll
  for (int i = 0; i < 2; ++i) {
    int c = tid + i * 256;
    int d = c >> 3, koff = (c & 7) * 8;
    int4v v = *(const int4v*)(&T[d * 72 + koff]);
    *(int4v*)(Ktb + ((bh << 6) + d) * (long)NTOK + n0 + koff) = v;
  }
}

// ---------------------------------------------------------------------------
// 4) flash attention, transposed orientation, reg-prefetch, swizzled LDS.
//    Split-KV: blockIdx.z = key-half; partial (unnormalized O^T, l) to ws
//    when nsplit>1, else direct normalized store. V == K (bug preserved).
// ---------------------------------------------------------------------------
__global__ __launch_bounds__(256) void attn_kernel(
    const bf16* __restrict__ Qb, const bf16* __restrict__ Kb, const bf16* __restrict__ Ktb,
    float* __restrict__ out, float* __restrict__ Opart, float* __restrict__ lpart,
    int nsplit) {
  __shared__ __align__(16) bf16 QP[128 * 64];  // Q tile, then P [qrow][key]
  __shared__ __align__(16) bf16 Ks[64 * 64];   // K  [key][d]
  __shared__ __align__(16) bf16 Kts[64 * 64];  // Kt [d][key]

  const int tid = threadIdx.x;
  const int w = tid >> 6, lane = tid & 63, l15 = lane & 15, quad = lane >> 4;
  const int q0 = blockIdx.x * 128;
  const int bh = blockIdx.y;
  const int half = blockIdx.z;
  const int b = bh / NH, h = bh % NH;
  const int ktiles = (NTOK / 64) / nsplit;
  const int kt0 = half * ktiles, kt1 = kt0 + ktiles;
  const bf16* Qhead  = Qb  + (long)bh * NTOK * HD;
  const bf16* Khead  = Kb  + (long)bh * NTOK * HD;
  const bf16* Kthead = Ktb + (long)bh * HD * NTOK;

  // per-thread staging geometry
  const int srow = tid >> 3, scb = (tid & 7) * 16, soff = (tid & 7) * 8;
  const bf16* pk  = Khead  + (long)srow * HD + soff;    // +i*32 rows
  const bf16* pkt = Kthead + (long)srow * NTOK + soff;  // +i*32 rows

  // stage Q tile (128 x 64)
#pragma unroll
  for (int i = 0; i < 4; ++i) {
    int c = tid + i * 256;
    int row = c >> 3, cb = (c & 7) * 16;
    int4v v = *(const int4v*)(Qhead + (long)(q0 + row) * HD + (c & 7) * 8);
    *(int4v*)swz(QP, row, cb) = v;
  }

  // prefetch tile kt0
  int4v rK[2], rKt[2];
#pragma unroll
  for (int i = 0; i < 2; ++i) {
    rK[i]  = *(const int4v*)(pk  + (long)kt0 * 64 * HD + (long)i * 32 * HD);
    rKt[i] = *(const int4v*)(pkt + (long)kt0 * 64 + (long)i * 32 * NTOK);
  }

  __syncthreads();
  // Q^T B-frags: B[k=d][n=qrow], lane l15 = qrow, k = quad*8+j (+32*kk)
  bf16x8 bq[2][2];
#pragma unroll
  for (int nt = 0; nt < 2; ++nt)
#pragma unroll
    for (int kk = 0; kk < 2; ++kk)
      bq[nt][kk] = *(const bf16x8*)swz(QP, w * 32 + nt * 16 + l15, kk * 64 + quad * 16);

  f32x4 o[4][2] = {};          // O^T: mt over d (4), nt over qrow (2)
  float lacc[2] = {0.f, 0.f};  // per-lane partial softmax denominators

  for (int kt = kt0; kt < kt1; ++kt) {
    __syncthreads();  // prev tile's LDS reads done (incl. Q frags at kt0)
#pragma unroll
    for (int i = 0; i < 2; ++i) {
      *(int4v*)swz(Ks,  srow + i * 32, scb) = rK[i];
      *(int4v*)swz(Kts, srow + i * 32, scb) = rKt[i];
    }
    __syncthreads();

    // prefetch tile kt+1 while computing tile kt (clamped at the end)
    const long knext = (long)((kt == kt1 - 1) ? kt : kt + 1) * 64;
#pragma unroll
    for (int i = 0; i < 2; ++i) {
      rK[i]  = *(const int4v*)(pk  + knext * HD + (long)i * 32 * HD);
      rKt[i] = *(const int4v*)(pkt + knext + (long)i * 32 * NTOK);
    }

    // S^T = K Q^T : s[mt][nt], rows (quad*4+reg) = keys, col (l15) = qrow
    f32x4 s[4][2] = {};
#pragma unroll
    for (int kk = 0; kk < 2; ++kk) {
      bf16x8 ak[4];
#pragma unroll
      for (int mt = 0; mt < 4; ++mt)
        ak[mt] = *(const bf16x8*)swz(Ks, mt * 16 + l15, kk * 64 + quad * 16);
#pragma unroll
      for (int mt = 0; mt < 4; ++mt)
#pragma unroll
        for (int nt = 0; nt < 2; ++nt)
          s[mt][nt] = __builtin_amdgcn_mfma_f32_16x16x32_bf16(ak[mt], bq[nt][kk], s[mt][nt], 0, 0, 0);
    }

    // P = exp2(S): no max subtraction; per-lane l accumulation; P -> LDS
#pragma unroll
    for (int mt = 0; mt < 4; ++mt)
#pragma unroll
      for (int nt = 0; nt < 2; ++nt) {
        f32x4 p;
#pragma unroll
        for (int reg = 0; reg < 4; ++reg) p[reg] = __builtin_amdgcn_exp2f(s[mt][nt][reg]);
        lacc[nt] += (p[0] + p[1]) + (p[2] + p[3]);
        // 4 regs = 4 consecutive keys -> packed 8B store, wave-private row
        *(bf16x4*)swz(QP, w * 32 + nt * 16 + l15, mt * 32 + quad * 8) =
            __builtin_convertvector(p, bf16x4);
      }
    // no barrier: each wave reads back only its own 32 qrows of QP

    // O^T += V^T P^T : A from Kts [d][key], B from QP (P) [qrow][key]
#pragma unroll
    for (int kk = 0; kk < 2; ++kk) {
      bf16x8 av[4], bp[2];
#pragma unroll
      for (int mt = 0; mt < 4; ++mt)
        av[mt] = *(const bf16x8*)swz(Kts, mt * 16 + l15, kk * 64 + quad * 16);
#pragma unroll
      for (int nt = 0; nt < 2; ++nt)
        bp[nt] = *(const bf16x8*)swz(QP, w * 32 + nt * 16 + l15, kk * 64 + quad * 16);
#pragma unroll
      for (int mt = 0; mt < 4; ++mt)
#pragma unroll
        for (int nt = 0; nt < 2; ++nt)
          o[mt][nt] = __builtin_amdgcn_mfma_f32_16x16x32_bf16(av[mt], bp[nt], o[mt][nt], 0, 0, 0);
    }
  }

  if (nsplit == 1) {
    // epilogue: reduce l across quads, scale, store fp32 out[b,n,h*64+d]
#pragma unroll
    for (int nt = 0; nt < 2; ++nt) {
      float l = lacc[nt];
      l += __shfl_xor(l, 16, 64);
      l += __shfl_xor(l, 32, 64);
      float rl = 1.0f / l;
      int n = q0 + w * 32 + nt * 16 + l15;
#pragma unroll
      for (int mt = 0; mt < 4; ++mt) {
        f32x4 v;
#pragma unroll
        for (int reg = 0; reg < 4; ++reg) v[reg] = o[mt][nt][reg] * rl;
        *(f32x4*)(&out[((long)(b * NTOK + n)) * CDIM + h * HD + mt * 16 + quad * 4]) = v;
      }
    }
  } else {
    // partial epilogue: unnormalized O^T + l to workspace
    const long rbase = ((long)(half * 2 * NH + bh)) << 12;  // row id incl. split
#pragma unroll
    for (int nt = 0; nt < 2; ++nt) {
      float l = lacc[nt];
      l += __shfl_xor(l, 16, 64);
      l += __shfl_xor(l, 32, 64);
      int n = q0 + w * 32 + nt * 16 + l15;
      if (quad == 0) lpart[rbase + n] = l;
#pragma unroll
      for (int mt = 0; mt < 4; ++mt)
        *(f32x4*)(&Opart[((rbase + n) << 6) + mt * 16 + quad * 4]) = o[mt][nt];
    }
  }
}

// ---------------------------------------------------------------------------
// 5) split-KV combine: out = (O0 + O1) / (l0 + l1)
// ---------------------------------------------------------------------------
__global__ __launch_bounds__(256) void combine_kernel(
    const float* __restrict__ Opart, const float* __restrict__ lpart,
    float* __restrict__ out) {
  const int t = threadIdx.x;
  const long r = (long)blockIdx.x * 16 + (t >> 4);  // row 0..(24*4096-1)
  const int d = (t & 15) * 4;
  const long RS = (long)2 * NH * NTOK;  // split stride in rows
  f32x4 a = *(const f32x4*)(Opart + (r << 6) + d);
  f32x4 c = *(const f32x4*)(Opart + ((RS + r) << 6) + d);
  float l = lpart[r] + lpart[RS + r];
  float rl = 1.0f / l;
  int bh = (int)(r >> 12), n = (int)(r & (NTOK - 1));
  int b = bh / NH, h = bh % NH;
  f32x4 v;
#pragma unroll
  for (int e = 0; e < 4; ++e) v[e] = (a[e] + c[e]) * rl;
  *(f32x4*)(&out[((long)(b * NTOK + n)) * CDIM + h * HD + d]) = v;
}

// ---------------------------------------------------------------------------
extern "C" void kernel_launch(void* const* d_in, const int* in_sizes, int n_in,
                              void* d_out, int out_size, void* d_ws, size_t ws_size,
                              hipStream_t stream) {
  const float* x  = (const float*)d_in[0];
  const float* Wq = (const float*)d_in[1];
  const float* Wk = (const float*)d_in[2];
  // d_in[3] (Wv) intentionally unused — reference bug preserved
  float* out = (float*)d_out;
  char* ws = (char*)d_ws;

  const long NX = (long)2 * NTOK * CDIM;  // 6291456 elems
  const long NW = (long)CDIM * CDIM;      // 589824 elems

  // workspace layout (bytes). Kt aliases xb (xb dead after proj_kernel).
  bf16* xb  = (bf16*)(ws);
  bf16* Ktb = (bf16*)(ws);
  bf16* wqb = (bf16*)(ws + NX * 2);
  bf16* wkb = (bf16*)(ws + NX * 2 + NW * 2);
  bf16* Qb  = (bf16*)(ws + NX * 2 + NW * 4);
  bf16* Kb  = (bf16*)(ws + NX * 2 + NW * 4 + NX * 2);
  const size_t base = (size_t)(NX * 6 + NW * 4);  // ~40.1 MB

  // split-KV partials (fp32) after base region
  const long ROWS = (long)2 * NH * NTOK;          // 98304 rows per split
  float* Opart = (float*)(ws + base);
  float* lpart = (float*)(ws + base + (size_t)2 * ROWS * HD * 4);
  const size_t need = base + (size_t)2 * ROWS * HD * 4 + (size_t)2 * ROWS * 4;
  const int nsplit = (ws_size >= need) ? 2 : 1;

  long tot4 = (NX + 2 * NW) / 4;
  cast_kernel<<<dim3((tot4 + 255) / 256), 256, 0, stream>>>(x, Wq, Wk, xb, wqb, wkb, NX, NW);
  proj_kernel<<<dim3(8192 / 128, CDIM / 128, 2), 256, 0, stream>>>(xb, wqb, wkb, Qb, Kb);
  transpose_kernel<<<dim3(NTOK / 64, 2 * NH), 256, 0, stream>>>(Kb, Ktb);
  attn_kernel<<<dim3(NTOK / 128, 2 * NH, nsplit), 256, 0, stream>>>(
      Qb, Kb, Ktb, out, Opart, lpart, nsplit);
  if (nsplit == 2)
    combine_kernel<<<dim3(ROWS / 16), 256, 0, stream>>>(Opart, lpart, out);
}

// Round 7
// 249.957 us; speedup vs baseline: 1.0105x; 1.0105x over previous
//
#include <hip/hip_runtime.h>

typedef __bf16 bf16;
typedef __bf16 bf16x4 __attribute__((ext_vector_type(4)));
typedef __bf16 bf16x8 __attribute__((ext_vector_type(8)));
typedef float  f32x4  __attribute__((ext_vector_type(4)));
typedef int    int4v  __attribute__((ext_vector_type(4)));

#define NTOK 4096
#define NH   12
#define HD   64
#define CDIM 768

// C^-0.5 * log2(e), folded into Q at projection time
#define K2SCALE 0.05205928442089389f

// XOR-swizzled LDS addressing: rows are 64 bf16 = 128 B = 8 x 16B blocks.
// block' = block ^ (row & 7). Conflict-free for b128 staging writes, b128
// fragment reads, b64 P writes.
__device__ __forceinline__ bf16* swz(bf16* base, int row, int byteoff) {
  return (bf16*)((char*)base + row * 128 +
                 ((((byteoff >> 4) ^ (row & 7)) << 4) | (byteoff & 15)));
}
__device__ __forceinline__ const bf16* swz(const bf16* base, int row, int byteoff) {
  return (const bf16*)((const char*)base + row * 128 +
                 ((((byteoff >> 4) ^ (row & 7)) << 4) | (byteoff & 15)));
}

// ---------------------------------------------------------------------------
// 1) fp32 -> bf16 cast for x, Wq, Wk
// ---------------------------------------------------------------------------
__global__ __launch_bounds__(256) void cast_kernel(
    const float* __restrict__ x, const float* __restrict__ wq, const float* __restrict__ wk,
    bf16* __restrict__ xb, bf16* __restrict__ wqb, bf16* __restrict__ wkb,
    long nx, long nw) {
  long i4 = ((long)blockIdx.x * 256 + threadIdx.x) * 4;
  if (i4 >= nx + 2 * nw) return;
  const float* src; bf16* dst;
  if (i4 < nx)            { src = x  + i4;            dst = xb  + i4; }
  else if (i4 < nx + nw)  { src = wq + (i4 - nx);     dst = wqb + (i4 - nx); }
  else                    { src = wk + (i4 - nx - nw); dst = wkb + (i4 - nx - nw); }
  f32x4 v = *(const f32x4*)src;
  *(bf16x4*)dst = __builtin_convertvector(v, bf16x4);
}

// ---------------------------------------------------------------------------
// 2) projection GEMM: y[m,j] = sum_k x[m,k] * W[j,k]   (y = x @ W^T)
//    tile 128x128, BK=64, reg-prefetch staging, swizzled LDS.
//    blockIdx.z: 0->Q(scaled), 1->K. out layout [B, H, N, 64]
// ---------------------------------------------------------------------------
__global__ __launch_bounds__(256) void proj_kernel(
    const bf16* __restrict__ xb, const bf16* __restrict__ wqb, const bf16* __restrict__ wkb,
    bf16* __restrict__ Qb, bf16* __restrict__ Kb) {
  __shared__ __align__(16) bf16 Ap[128 * 64];
  __shared__ __align__(16) bf16 Bp[128 * 64];
  const int tid = threadIdx.x;
  const int w = tid >> 6, lane = tid & 63, l15 = lane & 15, quad = lane >> 4;
  const int m0 = blockIdx.x * 128;
  const int j0 = blockIdx.y * 128;
  const bf16* W   = blockIdx.z ? wkb : wqb;
  bf16*       Out = blockIdx.z ? Kb  : Qb;
  const float oscale = blockIdx.z ? 1.0f : K2SCALE;

  const int srow = tid >> 3, scb = (tid & 7) * 16, soff = (tid & 7) * 8;
  const bf16* pa = xb + (long)(m0 + srow) * CDIM + soff;
  const bf16* pb = W  + (long)(j0 + srow) * CDIM + soff;

  f32x4 acc[2][8] = {};
  int4v rA[4], rB[4];
#pragma unroll
  for (int i = 0; i < 4; ++i) {
    rA[i] = *(const int4v*)(pa + (long)i * 32 * CDIM);
    rB[i] = *(const int4v*)(pb + (long)i * 32 * CDIM);
  }

  for (int kt = 0; kt < CDIM / 64; ++kt) {
    __syncthreads();
#pragma unroll
    for (int i = 0; i < 4; ++i) {
      *(int4v*)swz(Ap, srow + i * 32, scb) = rA[i];
      *(int4v*)swz(Bp, srow + i * 32, scb) = rB[i];
    }
    __syncthreads();
    const long koff = (long)((kt == CDIM / 64 - 1) ? kt : kt + 1) * 64;
#pragma unroll
    for (int i = 0; i < 4; ++i) {
      rA[i] = *(const int4v*)(pa + (long)i * 32 * CDIM + koff);
      rB[i] = *(const int4v*)(pb + (long)i * 32 * CDIM + koff);
    }
#pragma unroll
    for (int kk = 0; kk < 2; ++kk) {
      bf16x8 a[2], b[8];
#pragma unroll
      for (int rt = 0; rt < 2; ++rt)
        a[rt] = *(const bf16x8*)swz(Ap, w * 32 + rt * 16 + l15, kk * 64 + quad * 16);
#pragma unroll
      for (int ct = 0; ct < 8; ++ct)
        b[ct] = *(const bf16x8*)swz(Bp, ct * 16 + l15, kk * 64 + quad * 16);
#pragma unroll
      for (int rt = 0; rt < 2; ++rt)
#pragma unroll
        for (int ct = 0; ct < 8; ++ct)
          acc[rt][ct] = __builtin_amdgcn_mfma_f32_16x16x32_bf16(a[rt], b[ct], acc[rt][ct], 0, 0, 0);
    }
  }
#pragma unroll
  for (int rt = 0; rt < 2; ++rt)
#pragma unroll
    for (int ct = 0; ct < 8; ++ct)
#pragma unroll
      for (int reg = 0; reg < 4; ++reg) {
        int m = m0 + w * 32 + rt * 16 + quad * 4 + reg;
        int j = j0 + ct * 16 + l15;
        int b = m >> 12, n = m & (NTOK - 1);
        int h = j >> 6, d = j & (HD - 1);
        Out[(((long)(b * NH + h) * NTOK + n) << 6) + d] = (bf16)(acc[rt][ct][reg] * oscale);
      }
}

// ---------------------------------------------------------------------------
// 3) K [B,H,N,64] -> Kt [B,H,64,N]
// ---------------------------------------------------------------------------
__global__ __launch_bounds__(256) void transpose_kernel(
    const bf16* __restrict__ Kb, bf16* __restrict__ Ktb) {
  __shared__ __align__(16) bf16 T[64 * 72];
  const int tid = threadIdx.x;
  const int n0 = blockIdx.x * 64;
  const long bh = blockIdx.y;
#pragma unroll
  for (int i = 0; i < 2; ++i) {
    int c = tid + i * 256;
    int row = c >> 3, off = (c & 7) * 8;
    bf16x8 v = *(const bf16x8*)(Kb + ((bh << 12) + n0 + row) * HD + off);
#pragma unroll
    for (int e = 0; e < 8; ++e) T[(off + e) * 72 + row] = v[e];
  }
  __syncthreads();
#pragma unroll
  for (int i = 0; i < 2; ++i) {
    int c = tid + i * 256;
    int d = c >> 3, koff = (c & 7) * 8;
    int4v v = *(const int4v*)(&T[d * 72 + koff]);
    *(int4v*)(Ktb + ((bh << 6) + d) * (long)NTOK + n0 + koff) = v;
  }
}

// ---------------------------------------------------------------------------
// 4) flash attention, wave-split: qhalf = w>>1 owns 64 q-rows, khalf = w&1
//    owns a 32-key slice of each 64-key tile. Staging = register prefetch
//    (proven deterministic; glds-DMA dbuf reverted after round-6 tripwire).
//    O^T and l are key-slice partials, combined across the wave pair via LDS
//    at the epilogue (linear: no max subtraction used).
//    V == K (reference bug preserved). scale folded into Q.
// ---------------------------------------------------------------------------
__global__ __launch_bounds__(256) void attn_kernel(
    const bf16* __restrict__ Qb, const bf16* __restrict__ Kb, const bf16* __restrict__ Ktb,
    float* __restrict__ out) {
  // one block: [QP 128x64 | Ks 64x64 | Kts 64x64 | lbuf 512 f32] = 34 KB.
  // qhalf=1 epilogue scratch = Ks..Kts span (16 KB contiguous).
  __shared__ __align__(16) bf16 SH[128 * 64 + 64 * 64 + 64 * 64 + 1024];
  bf16* QP  = SH;                // Q tile, then P [qrow][key]
  bf16* Ks  = SH + 128 * 64;     // K  [key][d]
  bf16* Kts = SH + 128 * 64 + 64 * 64;  // Kt [d][key]
  float* lbuf = (float*)(SH + 128 * 64 + 2 * 64 * 64);  // 512 floats

  const int tid = threadIdx.x;
  const int w = tid >> 6, lane = tid & 63, l15 = lane & 15, quad = lane >> 4;
  const int qhalf = w >> 1, khalf = w & 1;
  const int q0 = blockIdx.x * 128;
  const int bh = blockIdx.y;
  const int b = bh / NH, h = bh % NH;
  const bf16* Qhead  = Qb  + (long)bh * NTOK * HD;
  const bf16* Khead  = Kb  + (long)bh * NTOK * HD;
  const bf16* Kthead = Ktb + (long)bh * HD * NTOK;

  // staging geometry (reg prefetch): rows srow, srow+32; 16B chunk (tid&7)
  const int srow = tid >> 3, scb = (tid & 7) * 16, soff = (tid & 7) * 8;
  const bf16* pk  = Khead  + (long)srow * HD + soff;
  const bf16* pkt = Kthead + (long)srow * NTOK + soff;

  // stage Q tile (128 x 64)
#pragma unroll
  for (int i = 0; i < 4; ++i) {
    int c = tid + i * 256;
    int row = c >> 3, cb = (c & 7) * 16;
    int4v v = *(const int4v*)(Qhead + (long)(q0 + row) * HD + (c & 7) * 8);
    *(int4v*)swz(QP, row, cb) = v;
  }

  // prefetch tile 0 into regs
  int4v rK[2], rKt[2];
#pragma unroll
  for (int i = 0; i < 2; ++i) {
    rK[i]  = *(const int4v*)(pk  + (long)i * 32 * HD);
    rKt[i] = *(const int4v*)(pkt + (long)i * 32 * NTOK);
  }

  __syncthreads();  // Q visible
  // Q^T B-frags (persistent): B[k=d][n=qrow], lane l15 = qrow
  bf16x8 bq[4][2];
#pragma unroll
  for (int nt = 0; nt < 4; ++nt)
#pragma unroll
    for (int kk = 0; kk < 2; ++kk)
      bq[nt][kk] = *(const bf16x8*)swz(QP, qhalf * 64 + nt * 16 + l15, kk * 64 + quad * 16);

  f32x4 o[4][4] = {};                    // O^T: mt over d, nt over qrow
  float lacc[4] = {0.f, 0.f, 0.f, 0.f};  // per-lane partial denominators

  for (int kt = 0; kt < NTOK / 64; ++kt) {
    __syncthreads();  // prev tile's LDS reads done (and Q-frag reads at kt=0)
#pragma unroll
    for (int i = 0; i < 2; ++i) {
      *(int4v*)swz(Ks,  srow + i * 32, scb) = rK[i];
      *(int4v*)swz(Kts, srow + i * 32, scb) = rKt[i];
    }
    __syncthreads();

    // prefetch tile kt+1 while computing tile kt (clamped at the end)
    const long knext = (long)((kt == NTOK / 64 - 1) ? kt : kt + 1) * 64;
#pragma unroll
    for (int i = 0; i < 2; ++i) {
      rK[i]  = *(const int4v*)(pk  + knext * HD + (long)i * 32 * HD);
      rKt[i] = *(const int4v*)(pkt + knext + (long)i * 32 * NTOK);
    }

    // S^T = K Q^T on this wave's 32-key slice: keys khalf*32 + mt*16 + ...
    f32x4 s[2][4] = {};
#pragma unroll
    for (int kk = 0; kk < 2; ++kk) {
      bf16x8 ak[2];
#pragma unroll
      for (int mt = 0; mt < 2; ++mt)
        ak[mt] = *(const bf16x8*)swz(Ks, khalf * 32 + mt * 16 + l15, kk * 64 + quad * 16);
#pragma unroll
      for (int mt = 0; mt < 2; ++mt)
#pragma unroll
        for (int nt = 0; nt < 4; ++nt)
          s[mt][nt] = __builtin_amdgcn_mfma_f32_16x16x32_bf16(ak[mt], bq[nt][kk], s[mt][nt], 0, 0, 0);
    }

    // P = exp2(S); per-lane l; P -> LDS [qrow][key] (wave-private bytes)
#pragma unroll
    for (int mt = 0; mt < 2; ++mt)
#pragma unroll
      for (int nt = 0; nt < 4; ++nt) {
        f32x4 p;
#pragma unroll
        for (int reg = 0; reg < 4; ++reg) p[reg] = __builtin_amdgcn_exp2f(s[mt][nt][reg]);
        lacc[nt] += (p[0] + p[1]) + (p[2] + p[3]);
        *(bf16x4*)swz(QP, qhalf * 64 + nt * 16 + l15, khalf * 64 + mt * 32 + quad * 8) =
            __builtin_convertvector(p, bf16x4);
      }

    // O^T += V^T P^T over the 32-key slice (single K=32 MFMA step)
    bf16x8 av[4], bp[4];
#pragma unroll
    for (int mt = 0; mt < 4; ++mt)
      av[mt] = *(const bf16x8*)swz(Kts, mt * 16 + l15, khalf * 64 + quad * 16);
#pragma unroll
    for (int nt = 0; nt < 4; ++nt)
      bp[nt] = *(const bf16x8*)swz(QP, qhalf * 64 + nt * 16 + l15, khalf * 64 + quad * 16);
#pragma unroll
    for (int mt = 0; mt < 4; ++mt)
#pragma unroll
      for (int nt = 0; nt < 4; ++nt)
        o[mt][nt] = __builtin_amdgcn_mfma_f32_16x16x32_bf16(av[mt], bp[nt], o[mt][nt], 0, 0, 0);
  }

  // ---- epilogue: combine across the wave pair (khalf 0/1), normalize, store
  float lq[4];
#pragma unroll
  for (int nt = 0; nt < 4; ++nt) {
    float l = lacc[nt];
    l += __shfl_xor(l, 16, 64);
    l += __shfl_xor(l, 32, 64);
    lq[nt] = l;  // uniform across quads
  }
  __syncthreads();  // all loop LDS traffic done; QP/Ks/Kts reusable
  float* sc = qhalf ? (float*)Ks : (float*)QP;  // 16 KB scratch per pair
  if (khalf == 1) {
#pragma unroll
    for (int mt = 0; mt < 4; ++mt)
#pragma unroll
      for (int nt = 0; nt < 4; ++nt)
        *(f32x4*)(sc + ((mt * 4 + nt) * 64 + lane) * 4) = o[mt][nt];
#pragma unroll
    for (int nt = 0; nt < 4; ++nt) lbuf[qhalf * 256 + nt * 64 + lane] = lq[nt];
  }
  __syncthreads();
  if (khalf == 0) {
    float rl[4];
#pragma unroll
    for (int nt = 0; nt < 4; ++nt)
      rl[nt] = 1.0f / (lq[nt] + lbuf[qhalf * 256 + nt * 64 + lane]);
#pragma unroll
    for (int nt = 0; nt < 4; ++nt) {
      int n = q0 + qhalf * 64 + nt * 16 + l15;
#pragma unroll
      for (int mt = 0; mt < 4; ++mt) {
        f32x4 po = *(const f32x4*)(sc + ((mt * 4 + nt) * 64 + lane) * 4);
        f32x4 v;
#pragma unroll
        for (int reg = 0; reg < 4; ++reg) v[reg] = (o[mt][nt][reg] + po[reg]) * rl[nt];
        *(f32x4*)(&out[((long)(b * NTOK + n)) * CDIM + h * HD + mt * 16 + quad * 4]) = v;
      }
    }
  }
}

// ---------------------------------------------------------------------------
extern "C" void kernel_launch(void* const* d_in, const int* in_sizes, int n_in,
                              void* d_out, int out_size, void* d_ws, size_t ws_size,
                              hipStream_t stream) {
  const float* x  = (const float*)d_in[0];
  const float* Wq = (const float*)d_in[1];
  const float* Wk = (const float*)d_in[2];
  // d_in[3] (Wv) intentionally unused — reference bug preserved
  float* out = (float*)d_out;
  char* ws = (char*)d_ws;

  const long NX = (long)2 * NTOK * CDIM;  // 6291456 elems
  const long NW = (long)CDIM * CDIM;      // 589824 elems

  // workspace layout (bytes). Kt aliases xb (xb dead after proj_kernel).
  bf16* xb  = (bf16*)(ws);
  bf16* Ktb = (bf16*)(ws);
  bf16* wqb = (bf16*)(ws + NX * 2);
  bf16* wkb = (bf16*)(ws + NX * 2 + NW * 2);
  bf16* Qb  = (bf16*)(ws + NX * 2 + NW * 4);
  bf16* Kb  = (bf16*)(ws + NX * 2 + NW * 4 + NX * 2);
  // total required: NX*4 + NW*4 + NX*2 = ~40.1 MB

  long tot4 = (NX + 2 * NW) / 4;
  cast_kernel<<<dim3((tot4 + 255) / 256), 256, 0, stream>>>(x, Wq, Wk, xb, wqb, wkb, NX, NW);
  proj_kernel<<<dim3(8192 / 128, CDIM / 128, 2), 256, 0, stream>>>(xb, wqb, wkb, Qb, Kb);
  transpose_kernel<<<dim3(NTOK / 64, 2 * NH), 256, 0, stream>>>(Kb, Ktb);
  attn_kernel<<<dim3(NTOK / 128, 2 * NH), 256, 0, stream>>>(Qb, Kb, Ktb, out);
}